// Round 7
// baseline (46.816 us; speedup 1.0000x reference)
//
#include <hip/hip_runtime.h>
#include <hip/hip_bf16.h>
#include <math.h>

using short8   = __attribute__((ext_vector_type(8))) short;
using ushort4v = __attribute__((ext_vector_type(4))) unsigned short;
using float4v  = __attribute__((ext_vector_type(4))) float;

#define D_DIM 1024
#define NCLS  40
#define WSTR  1064
#define TM    64
#define NCH   16            // 1024 / 64 K-chunks
#define BATCH 32768

__device__ __forceinline__ short f2bf(float f) {
    __hip_bfloat16 h = __float2bfloat16(f);
    union { __hip_bfloat16 h; short s; } u; u.h = h;
    return u.s;
}

// ---- Kernel 1: pack W/W_rev into MFMA-fragment order (unchanged, verified):
//      Wfrag[((ch*2+ks)*5+t)*512 + lane*8 + e] = class(t*16+lane&15), k=ch*64+ks*32+(lane>>4)*8+e
__global__ void convert_w_kernel(const float* __restrict__ W, const float* __restrict__ Wr,
                                 short* __restrict__ Wfrag) {
    int idx  = blockIdx.x * 256 + threadIdx.x;
    int lane = idx & 63;
    int rest = idx >> 6;
    int t    = rest % 5;
    int rest2 = rest / 5;
    int ks   = rest2 & 1;
    int ch   = rest2 >> 1;
    int cls  = t * 16 + (lane & 15);
    int k0   = ch * 64 + ks * 32 + (lane >> 4) * 8;
    const float* srow = (cls < NCLS) ? (W + (size_t)cls * WSTR)
                                     : (Wr + (size_t)(cls - NCLS) * WSTR);
    short8 v;
#pragma unroll
    for (int e = 0; e < 8; ++e) v[e] = f2bf(srow[k0 + e]);
    *(short8*)(Wfrag + (size_t)idx * 8) = v;
}

// ---- Kernel 2: GEMM only (round-6 body, verified) -> transposed logits LgT[80][32768]
__global__ __launch_bounds__(256, 2) void bichain_gemm(
    const float* __restrict__ src, const short* __restrict__ Wfrag,
    float* __restrict__ LgT)
{
    // LDS: per-wave-private bf16 A tiles: 4 waves x 3 bufs x [16 rows][128B] = 24KB
    __shared__ __align__(16) char smem[24576];

    const int tid  = threadIdx.x;
    const int lane = tid & 63;
    const int wave = tid >> 6;
    const int row0 = blockIdx.x * TM;
    const int i16  = lane & 15;
    const int i4   = lane >> 4;

    char* ldsW = smem + wave * 6144;
    const float* aGlob = src + (size_t)(row0 + wave * 16 + i4) * D_DIM + i16 * 4;

    float4v ap[3][4];
    short8  wp[2][10];
    float4v acc[5];
#pragma unroll
    for (int t = 0; t < 5; ++t)
#pragma unroll
        for (int r = 0; r < 4; ++r) acc[t][r] = 0.f;

#define LOADA(ch) do { if ((ch) < NCH) {                                   \
    const float* _p = aGlob + (ch) * 64;                                   \
    ap[(ch)%3][0] = *(const float4v*)(_p);                                 \
    ap[(ch)%3][1] = *(const float4v*)(_p + 4 * D_DIM);                     \
    ap[(ch)%3][2] = *(const float4v*)(_p + 8 * D_DIM);                     \
    ap[(ch)%3][3] = *(const float4v*)(_p + 12 * D_DIM); } } while (0)

#define LOADW(ch) do { if ((ch) < NCH) {                                   \
    const short* _w = Wfrag + (size_t)(ch) * 5120 + (lane << 3);           \
    wp[(ch)%2][0] = *(const short8*)(_w + 0 * 512);                        \
    wp[(ch)%2][1] = *(const short8*)(_w + 1 * 512);                        \
    wp[(ch)%2][2] = *(const short8*)(_w + 2 * 512);                        \
    wp[(ch)%2][3] = *(const short8*)(_w + 3 * 512);                        \
    wp[(ch)%2][4] = *(const short8*)(_w + 4 * 512);                        \
    wp[(ch)%2][5] = *(const short8*)(_w + 5 * 512);                        \
    wp[(ch)%2][6] = *(const short8*)(_w + 6 * 512);                        \
    wp[(ch)%2][7] = *(const short8*)(_w + 7 * 512);                        \
    wp[(ch)%2][8] = *(const short8*)(_w + 8 * 512);                        \
    wp[(ch)%2][9] = *(const short8*)(_w + 9 * 512); } } while (0)

#define DSW1(ch, j) {                                                      \
    int _r = (j) * 4 + i4;                                                 \
    ushort4v _v;                                                           \
    _v[0] = (unsigned short)f2bf(ap[(ch)%3][j][0]);                        \
    _v[1] = (unsigned short)f2bf(ap[(ch)%3][j][1]);                        \
    _v[2] = (unsigned short)f2bf(ap[(ch)%3][j][2]);                        \
    _v[3] = (unsigned short)f2bf(ap[(ch)%3][j][3]);                        \
    *(ushort4v*)(_b + _r * 128 + ((i16 ^ ((_r & 7) << 1)) << 3)) = _v; }
#define DSW(ch) do { if ((ch) < NCH) {                                     \
    char* _b = ldsW + ((ch)%3) * 2048;                                     \
    DSW1(ch, 0) DSW1(ch, 1) DSW1(ch, 2) DSW1(ch, 3) } } while (0)

#define MFMA_(ch) do {                                                     \
    const char* _fb = ldsW + ((ch)%3) * 2048 + i16 * 128;                  \
    const int _sw = (i16 & 7) << 1;                                        \
    short8 _a0 = *(const short8*)(_fb + (((i4 * 2)     ^ _sw) << 3));      \
    acc[0] = __builtin_amdgcn_mfma_f32_16x16x32_bf16(_a0, wp[(ch)%2][0], acc[0], 0, 0, 0); \
    acc[1] = __builtin_amdgcn_mfma_f32_16x16x32_bf16(_a0, wp[(ch)%2][1], acc[1], 0, 0, 0); \
    acc[2] = __builtin_amdgcn_mfma_f32_16x16x32_bf16(_a0, wp[(ch)%2][2], acc[2], 0, 0, 0); \
    acc[3] = __builtin_amdgcn_mfma_f32_16x16x32_bf16(_a0, wp[(ch)%2][3], acc[3], 0, 0, 0); \
    acc[4] = __builtin_amdgcn_mfma_f32_16x16x32_bf16(_a0, wp[(ch)%2][4], acc[4], 0, 0, 0); \
    short8 _a1 = *(const short8*)(_fb + (((8 + i4 * 2) ^ _sw) << 3));      \
    acc[0] = __builtin_amdgcn_mfma_f32_16x16x32_bf16(_a1, wp[(ch)%2][5], acc[0], 0, 0, 0); \
    acc[1] = __builtin_amdgcn_mfma_f32_16x16x32_bf16(_a1, wp[(ch)%2][6], acc[1], 0, 0, 0); \
    acc[2] = __builtin_amdgcn_mfma_f32_16x16x32_bf16(_a1, wp[(ch)%2][7], acc[2], 0, 0, 0); \
    acc[3] = __builtin_amdgcn_mfma_f32_16x16x32_bf16(_a1, wp[(ch)%2][8], acc[3], 0, 0, 0); \
    acc[4] = __builtin_amdgcn_mfma_f32_16x16x32_bf16(_a1, wp[(ch)%2][9], acc[4], 0, 0, 0); \
  } while (0)

#define BODY(ch) do { LOADW((ch)+1); LOADA((ch)+3); DSW((ch)+1); MFMA_(ch); } while (0)

    LOADA(0); LOADA(1); LOADA(2); LOADW(0); DSW(0);
    BODY(0);  BODY(1);  BODY(2);  BODY(3);
    BODY(4);  BODY(5);  BODY(6);  BODY(7);
    BODY(8);  BODY(9);  BODY(10); BODY(11);
    BODY(12); BODY(13); BODY(14); BODY(15);

#undef LOADA
#undef LOADW
#undef DSW1
#undef DSW
#undef MFMA_
#undef BODY

    // C-write: acc[t] = rows (i4*4 .. +3) of class t*16+i16 -> one float4 per tile,
    // 16 classes x 4 contiguous 16B segments per instr (coalesced 64B/class)
#pragma unroll
    for (int t = 0; t < 5; ++t)
        *(float4v*)(LgT + (size_t)(t * 16 + i16) * BATCH + row0 + wave * 16 + i4 * 4) = acc[t];
}

// ---- Kernel 3: sequential chain, one thread per (row, dir), tail weights in LDS
__global__ __launch_bounds__(256) void bichain_chain(
    const float* __restrict__ LgT,
    const float* __restrict__ Wf, const float* __restrict__ Wr,
    const float* __restrict__ bf_, const float* __restrict__ br_,
    float* __restrict__ out)
{
    __shared__ float Tw[2][NCLS][NCLS];   // tail weights
    __shared__ float Tb[2][NCLS];         // biases
    __shared__ float Sc[128][81];         // scores (81 stride: conflict-free)

    const int tid = threadIdx.x;
    // stage tail weights + biases once per block (L2-hot, 13KB)
    for (int e = tid; e < 2 * NCLS * NCLS; e += 256) {
        int dir = e / (NCLS * NCLS);
        int rem = e - dir * (NCLS * NCLS);
        int i = rem / NCLS, j = rem - i * NCLS;
        const float* Wt = dir ? Wr : Wf;
        Tw[dir][i][j] = Wt[(size_t)i * WSTR + D_DIM + j];
    }
    if (tid < 2 * NCLS) {
        int dir = tid / NCLS, i = tid - dir * NCLS;
        Tb[dir][i] = dir ? br_[i] : bf_[i];
    }
    __syncthreads();

    const int rl  = tid & 127;           // local row
    const int dir = tid >> 7;            // wave-uniform direction (waves 0,1 fwd; 2,3 rev)
    const int row = blockIdx.x * 128 + rl;

    float s[NCLS];
#pragma unroll
    for (int i = 0; i < NCLS; ++i) {
        float z = LgT[(size_t)(dir * NCLS + i) * BATCH + row] + Tb[dir][i];
#pragma unroll
        for (int j = 0; j < i; ++j)
            z += s[j] * Tw[dir][i][j];           // LDS broadcast (all lanes same addr)
        s[i] = 1.f / (1.f + __expf(-z));
        Sc[rl][dir * NCLS + i] = s[i];
    }
    __syncthreads();

    // combine + coalesced write: out[:,c] = 0.5*(fwd[c] + rev[39-c])
    float* outp = out + (size_t)blockIdx.x * 128 * NCLS;
    for (int idx = tid; idx < 128 * NCLS; idx += 256) {
        int r2 = idx / NCLS, c = idx - r2 * NCLS;
        outp[idx] = 0.5f * (Sc[r2][c] + Sc[r2][NCLS + (NCLS - 1 - c)]);
    }
}

extern "C" void kernel_launch(void* const* d_in, const int* in_sizes, int n_in,
                              void* d_out, int out_size, void* d_ws, size_t ws_size,
                              hipStream_t stream) {
    const float* src = (const float*)d_in[0];
    // d_in[1] = attn_mask, unused by the reference
    const float* W   = (const float*)d_in[2];
    const float* b   = (const float*)d_in[3];
    const float* Wr  = (const float*)d_in[4];
    const float* br  = (const float*)d_in[5];
    float* out = (float*)d_out;
    short* Wfrag = (short*)d_ws;                            // 160KB fragment-ordered weights
    float* LgT   = (float*)((char*)d_ws + (1 << 20));       // 80 x 32768 fp32 logits^T (10.5MB)

    convert_w_kernel<<<40, 256, 0, stream>>>(W, Wr, Wfrag);
    bichain_gemm<<<512, 256, 0, stream>>>(src, Wfrag, LgT);
    bichain_chain<<<256, 256, 0, stream>>>(LgT, W, Wr, b, br, out);
}